// Round 13
// baseline (1892.511 us; speedup 1.0000x reference)
//
#include <hip/hip_runtime.h>
#include <math.h>

// Problem dims
#define NB   16
#define NC   1024
#define ND   256
#define NT_  9
#define TDIM 32

typedef _Float16 half8 __attribute__((ext_vector_type(8)));
typedef _Float16 half4v __attribute__((ext_vector_type(4)));
typedef float f32x4 __attribute__((ext_vector_type(4)));

#define GLL(gp, lp)                                                            \
  __builtin_amdgcn_global_load_lds(                                            \
      (const __attribute__((address_space(1))) void*)(gp),                     \
      (__attribute__((address_space(3))) void*)(lp), 16, 0, 0)

#define MFMA16(A, B, C) __builtin_amdgcn_mfma_f32_16x16x32_f16(A, B, C, 0, 0, 0)

// Tiled panel layouts (16B-chunk order == LDS image):
//  A-tile (32 rows x 32 k) = 1024 halves: element (row,k) ->
//    (((k&31)>>3)*32 + row)*8 + (k&7)
//  B-tile (256 n x 32 k) = 8192 halves: element (n,k) ->
//    (((k&31)>>3)*256 + n)*8 + (k&7)

// ---------------------------------------------------------------------------
__global__ __launch_bounds__(256) void k_copy_h0(const float* __restrict__ h0,
                                                 float* __restrict__ out) {
  size_t idx = (size_t)blockIdx.x * blockDim.x + threadIdx.x;
  size_t fe = idx * 4;
  size_t b = fe / ((size_t)NC * ND);
  size_t rem = fe % ((size_t)NC * ND);
  float4 v = *(const float4*)(h0 + fe);
  *(float4*)(out + (b * NT_) * (size_t)NC * ND + rem) = v;
}

// ---------------------------------------------------------------------------
__global__ __launch_bounds__(256) void k_deg(const float* __restrict__ adj,
                                             float* __restrict__ invdeg) {
  int wave = threadIdx.x >> 6;
  int lane = threadIdx.x & 63;
  int row = blockIdx.x * 4 + wave;
  const float* p = adj + (size_t)row * NC;
  float s = 0.f;
#pragma unroll
  for (int q = 0; q < 4; ++q) {
    float4 v = *(const float4*)(p + q * 256 + lane * 4);
    s += v.x + v.y + v.z + v.w;
  }
#pragma unroll
  for (int off = 32; off; off >>= 1) s += __shfl_down(s, off);
  if (lane == 0) invdeg[row] = 1.f / fmaxf(s, 1.f);
}

// ---------------------------------------------------------------------------
// adj f32 -> fp16, A-tiled: adjT[b][mq(32)][t(32)] each 1024 halves
__global__ __launch_bounds__(256) void k_split_adj(const float* __restrict__ adj,
                                                   _Float16* __restrict__ adjT) {
  int i = blockIdx.x * 256 + threadIdx.x;
  int k0 = (i & 255) * 4;
  int c = (i >> 8) & 1023;
  int b = i >> 18;
  float4 v = *(const float4*)(adj + (((size_t)b * NC + c) << 10) + k0);
  half4v h;
  h[0] = (_Float16)v.x; h[1] = (_Float16)v.y;
  h[2] = (_Float16)v.z; h[3] = (_Float16)v.w;
  int mq = c >> 5, t = k0 >> 5;
  size_t base = ((((size_t)b * 32 + mq) * 32) + t) * 1024;
  int chunk = ((k0 & 31) >> 3) * 32 + (c & 31);
  *(half4v*)(adjT + base + chunk * 8 + (k0 & 7)) = h;
}

// ---------------------------------------------------------------------------
// W1[0:512]^T, W2^T -> fp16, B-tiled: W1Tt[16 tiles][8192], W2Tt[8][8192]
__global__ __launch_bounds__(256) void k_split_w(const float* __restrict__ W1,
                                                 const float* __restrict__ W2,
                                                 _Float16* __restrict__ W1Tt,
                                                 _Float16* __restrict__ W2Tt) {
  int blk = blockIdx.x;
  int tid = threadIdx.x;
  if (blk < 128) {
    int i = blk * 256 + tid;
    int n = i & 255, k0 = (i >> 8) * 4;
    half4v h;
#pragma unroll
    for (int q = 0; q < 4; ++q) h[q] = (_Float16)W1[(size_t)(k0 + q) * ND + n];
    int t = k0 >> 5;
    int chunk = ((k0 & 31) >> 3) * 256 + n;
    *(half4v*)(W1Tt + (size_t)t * 8192 + chunk * 8 + (k0 & 7)) = h;
  } else {
    int i = (blk - 128) * 256 + tid;
    int n = i & 255, k0 = (i >> 8) * 4;
    half4v h;
#pragma unroll
    for (int q = 0; q < 4; ++q) h[q] = (_Float16)W2[(size_t)(k0 + q) * ND + n];
    int t = k0 >> 5;
    int chunk = ((k0 & 31) >> 3) * 256 + n;
    *(half4v*)(W2Tt + (size_t)t * 8192 + chunk * 8 + (k0 & 7)) = h;
  }
}

// ---------------------------------------------------------------------------
// one-time: h0 -> hHt/hLt (A-tiled [b][mq][ta(8)][1024]) + hTt (B-tiled
// [b][t(32)][8192], rows n=d, k=c)
__global__ __launch_bounds__(256) void k_htsplit(const float* __restrict__ src,
                                                 _Float16* __restrict__ hHt,
                                                 _Float16* __restrict__ hLt,
                                                 _Float16* __restrict__ hTt) {
  int i = blockIdx.x * 256 + threadIdx.x;
  int d0 = (i & 63) * 4;
  int c = (i >> 6) & 1023;
  int b = i >> 16;
  float4 v = *(const float4*)(src + (((size_t)b * NC + c) << 8) + d0);
  float vv[4] = {v.x, v.y, v.z, v.w};
  half4v hh, ll;
#pragma unroll
  for (int q = 0; q < 4; ++q) {
    _Float16 h = (_Float16)vv[q];
    hh[q] = h;
    ll[q] = (_Float16)(vv[q] - (float)h);
  }
  int mq = c >> 5, ta = d0 >> 5;
  size_t abase = ((((size_t)b * 32 + mq) * 8) + ta) * 1024;
  int achunk = ((d0 & 31) >> 3) * 32 + (c & 31);
  *(half4v*)(hHt + abase + achunk * 8 + (d0 & 7)) = hh;
  *(half4v*)(hLt + abase + achunk * 8 + (d0 & 7)) = ll;
  size_t tbase = ((size_t)b * 32 + mq) * 8192;
  int gk = (c & 31) >> 3, offc = c & 7;
#pragma unroll
  for (int q = 0; q < 4; ++q)
    hTt[tbase + (size_t)(gk * 256 + d0 + q) * 8 + offc] = hh[q];
}

// ---------------------------------------------------------------------------
// k_agg: agg = diag(invdeg) * (adj @ h), fp16 1-product. 128x64 tile,
// 256 thr (4 waves 2x2, wave-tile 64x32), dbuf + stage-ahead, 24KB LDS,
// grid 512 XCD-swizzled (batch -> one XCD). Writes aggT A-tiled.
__global__ __launch_bounds__(256) void k_agg(const _Float16* __restrict__ adjT,
                                             const _Float16* __restrict__ hTt,
                                             const float* __restrict__ invdeg,
                                             _Float16* __restrict__ aggT) {
  __shared__ __align__(16) _Float16 As[2][4096];  // 16 KB (128x32 A, dbuf)
  __shared__ __align__(16) _Float16 Bs[2][2048];  // 8 KB (64x32 B, dbuf)
  const int tid = threadIdx.x;
  const int lane = tid & 63, wid = tid >> 6;
  const int wm = wid >> 1, wn = wid & 1;
  const int g = lane >> 4, r = lane & 15, rg = (lane >> 4) * 4;
  // swizzle: batch b's 32 blocks (8m x 4n) share id mod 8 -> one XCD
  const int p = blockIdx.x;
  const int b = ((p >> 3) >> 5) * 8 + (p & 7);
  const int q32 = (p >> 3) & 31;
  const int m_t = q32 >> 2, n_t = q32 & 3;
  const int m0 = m_t * 128, n0 = n_t * 64;

  f32x4 acc[4][2] = {};

  // A: 4 consecutive mq-tiles (m0>>5 .. +3) of k-tile T; 512 chunks
#define STAGE_A(T, DST)                                                        \
  do {                                                                         \
    _Pragma("unroll") for (int c2 = 0; c2 < 2; ++c2) {                         \
      int e = c2 * 256 + tid;                                                  \
      int qq = e >> 7, ch = e & 127;                                           \
      GLL(adjT + ((((size_t)b * 32 + (m0 >> 5) + qq) * 32) + (T)) * 1024 +     \
              ch * 8,                                                          \
          (DST) + (size_t)e * 8);                                              \
    }                                                                          \
  } while (0)

  // B: 64-col slice [n0,n0+64) of hT B-tile T; 256 chunks
#define STAGE_Bh(T, DST)                                                       \
  do {                                                                         \
    int gk = tid >> 6, nn = tid & 63;                                          \
    GLL(hTt + ((size_t)b * 32 + (T)) * 8192 + (size_t)(gk * 256 + n0 + nn) * 8,\
        (DST) + (size_t)tid * 8);                                              \
  } while (0)

  STAGE_A(0, As[0]);
  STAGE_Bh(0, Bs[0]);
  __syncthreads();
  for (int t = 0; t < 32; ++t) {
    int cur = t & 1;
    if (t < 31) {
      STAGE_A(t + 1, As[cur ^ 1]);
      STAGE_Bh(t + 1, Bs[cur ^ 1]);
    }
    half8 Af[4], Bf[2];
#pragma unroll
    for (int i = 0; i < 4; ++i) {
      int row = wm * 64 + i * 16 + r;
      Af[i] = ((const half8*)As[cur])[((row >> 5) * 4 + g) * 32 + (row & 31)];
    }
#pragma unroll
    for (int j = 0; j < 2; ++j)
      Bf[j] = ((const half8*)Bs[cur])[g * 64 + wn * 32 + j * 16 + r];
#pragma unroll
    for (int i = 0; i < 4; ++i)
#pragma unroll
      for (int j = 0; j < 2; ++j) acc[i][j] = MFMA16(Af[i], Bf[j], acc[i][j]);
    __syncthreads();
  }
  // epilogue: invdeg scale -> aggT (A-tiled, hi only)
#pragma unroll
  for (int i = 0; i < 4; ++i) {
#pragma unroll
    for (int j = 0; j < 2; ++j) {
      int col = n0 + wn * 32 + j * 16 + r;
      int ta = col >> 5;
      int cgk = (col & 31) >> 3, offc = col & 7;
#pragma unroll
      for (int q = 0; q < 4; ++q) {
        int m = m0 + wm * 64 + i * 16 + rg + q;
        float v = acc[i][j][q] * invdeg[b * NC + m];
        size_t base = (((size_t)b * 32 + (m >> 5)) * 8 + ta) * 1024;
        aggT[base + (size_t)(cgk * 32 + (m & 31)) * 8 + offc] = (_Float16)v;
      }
    }
  }
#undef STAGE_A
#undef STAGE_Bh
}

// ---------------------------------------------------------------------------
// k_mlp: u = tanh([h|agg]@W1hi + b1eff); f = u@W2hi + b2; RK4 epilogue.
// grid 512 (XCD-swizzled), 512 thr = 8 waves along N, tile 32x256,
// wave-tile 32x32. dbuf + stage-ahead, coalesced tiled staging.
__global__ __launch_bounds__(512, 4) void k_mlp(
    _Float16* __restrict__ hHt, _Float16* __restrict__ hLt,
    const _Float16* __restrict__ aggT, _Float16* __restrict__ hTw,
    const _Float16* __restrict__ W1Tt, const _Float16* __restrict__ W2Tt,
    const float* __restrict__ W1, const float* __restrict__ b1,
    const float* __restrict__ b2, const float* __restrict__ tg,
    int step, int stage, float* __restrict__ out, float* __restrict__ accws) {
  __shared__ __align__(16) _Float16 Bs[2][8192];  // 32 KB B dbuf
  __shared__ __align__(16) _Float16 As[2][2048];  // 8 KB A (hi | lo) dbuf
  __shared__ __align__(16) _Float16 uS[8192];     // 16 KB
  __shared__ float te_s[TDIM];
  __shared__ float b1s[256];

  const int tid = threadIdx.x;
  const int lane = tid & 63, wid = tid >> 6;
  const int g = lane >> 4, r = lane & 15, rg = (lane >> 4) * 4;
  const int p = blockIdx.x;
  const int b = ((p >> 3) >> 5) * 8 + (p & 7);
  const int mq = (p >> 3) & 31;

  const _Float16* hHb = hHt + (((size_t)b * 32 + mq) * 8) * 1024;
  const _Float16* hLb = hLt + (((size_t)b * 32 + mq) * 8) * 1024;
  const _Float16* aggB = aggT + (((size_t)b * 32 + mq) * 8) * 1024;

  f32x4 acc[2][2] = {};

#define STAGE_B(SRC, DST)                                                      \
  do {                                                                         \
    GLL((SRC) + (size_t)tid * 8, (DST) + (size_t)tid * 8);                     \
    GLL((SRC) + (size_t)(512 + tid) * 8, (DST) + (size_t)(512 + tid) * 8);     \
  } while (0)

#define STAGE_AHL(TA, DST)                                                     \
  do {                                                                         \
    if (tid < 128)                                                             \
      GLL(hHb + (size_t)(TA) * 1024 + tid * 8, (DST) + (size_t)tid * 8);       \
    else if (tid < 256)                                                        \
      GLL(hLb + (size_t)(TA) * 1024 + (tid - 128) * 8,                         \
          (DST) + 1024 + (size_t)(tid - 128) * 8);                             \
  } while (0)

#define STAGE_AGG(TA, DST)                                                     \
  do {                                                                         \
    if (tid < 128)                                                             \
      GLL(aggB + (size_t)(TA) * 1024 + tid * 8, (DST) + (size_t)tid * 8);      \
  } while (0)

  // ---- prologue ----
  STAGE_AHL(0, As[0]);
  STAGE_B(W1Tt, Bs[0]);
  if (tid < 16) {
    float t0 = tg[step], t1 = tg[step + 1];
    float frac = (stage == 0) ? 0.f : ((stage == 3) ? 1.f : 0.5f);
    float t = t0 + frac * (t1 - t0);
    float f = expf(-logf(10000.f) * (float)tid / 16.f);
    te_s[tid] = sinf(t * f);
    te_s[tid + 16] = cosf(t * f);
  }
  __syncthreads();
  if (tid < 256) {
    float s = b1[tid];
#pragma unroll
    for (int q = 0; q < TDIM; ++q)
      s = fmaf(te_s[q], W1[(size_t)(512 + q) * ND + tid], s);
    b1s[tid] = s;
  }

  // ---- phase A: K=512 over [h | agg]; B = W1T-hi ----
  for (int t = 0; t < 16; ++t) {
    int cur = t & 1;
    if (t < 15) {
      if (t + 1 < 8) STAGE_AHL(t + 1, As[cur ^ 1]);
      else STAGE_AGG(t + 1 - 8, As[cur ^ 1]);
      STAGE_B(W1Tt + (size_t)(t + 1) * 8192, Bs[cur ^ 1]);
    } else {
      STAGE_B(W2Tt, Bs[cur ^ 1]);
    }
    half8 AH[2], AL[2], Bf[2];
    const bool hasL = (t < 8);
#pragma unroll
    for (int i = 0; i < 2; ++i) {
      AH[i] = ((const half8*)As[cur])[g * 32 + i * 16 + r];
      AL[i] = ((const half8*)(As[cur] + 1024))[g * 32 + i * 16 + r];
    }
#pragma unroll
    for (int j = 0; j < 2; ++j)
      Bf[j] = ((const half8*)Bs[cur])[g * 256 + wid * 32 + j * 16 + r];
#pragma unroll
    for (int i = 0; i < 2; ++i)
#pragma unroll
      for (int j = 0; j < 2; ++j) {
        acc[i][j] = MFMA16(AH[i], Bf[j], acc[i][j]);
        if (hasL) acc[i][j] = MFMA16(AL[i], Bf[j], acc[i][j]);
      }
    __syncthreads();
  }
  // transition: uS = tanh(acc + b1eff)
#pragma unroll
  for (int i = 0; i < 2; ++i) {
#pragma unroll
    for (int j = 0; j < 2; ++j) {
      int col = wid * 32 + j * 16 + r;
#pragma unroll
      for (int q = 0; q < 4; ++q) {
        int row = i * 16 + rg + q;
        float v = tanhf(acc[i][j][q] + b1s[col]);
        uS[((col >> 3) * 32 + row) * 8 + (col & 7)] = (_Float16)v;
      }
      acc[i][j] = (f32x4){0.f, 0.f, 0.f, 0.f};
    }
  }
  __syncthreads();

  // ---- phase B: K=256 over u; B = W2T-hi ----
  for (int t = 0; t < 8; ++t) {
    int cur = t & 1;
    if (t < 7) STAGE_B(W2Tt + (size_t)(t + 1) * 8192, Bs[cur ^ 1]);
    half8 Af[2], Bf[2];
#pragma unroll
    for (int i = 0; i < 2; ++i)
      Af[i] = ((const half8*)uS)[(t * 4 + g) * 32 + i * 16 + r];
#pragma unroll
    for (int j = 0; j < 2; ++j)
      Bf[j] = ((const half8*)Bs[cur])[g * 256 + wid * 32 + j * 16 + r];
#pragma unroll
    for (int i = 0; i < 2; ++i)
#pragma unroll
      for (int j = 0; j < 2; ++j) acc[i][j] = MFMA16(Af[i], Bf[j], acc[i][j]);
    __syncthreads();
  }
  // ---- RK4 epilogue ----
  const float t0 = tg[step], t1 = tg[step + 1];
  const float dt = t1 - t0;
  const float cs = (stage == 2) ? dt : 0.5f * dt;
#pragma unroll
  for (int i = 0; i < 2; ++i) {
#pragma unroll
    for (int j = 0; j < 2; ++j) {
      int col = wid * 32 + j * 16 + r;
      float bb2 = b2[col];
      int ii0 = mq * 32 + i * 16 + rg;
      size_t hrow = (((size_t)b * NT_ + step) * NC + ii0) * (size_t)ND + col;
      size_t wrow = ((size_t)b * NC + ii0) * (size_t)ND + col;
      float val[4];
#pragma unroll
      for (int q = 0; q < 4; ++q) {
        float f = acc[i][j][q] + bb2;
        float hb = out[hrow + (size_t)q * ND];
        size_t widx = wrow + (size_t)q * ND;
        if (stage == 0) {
          accws[widx] = f;
          val[q] = hb + cs * f;
        } else if (stage == 3) {
          float hn = hb + (dt / 6.f) * (accws[widx] + f);
          out[hrow + (size_t)NC * ND + (size_t)q * ND] = hn;
          val[q] = hn;
        } else {
          accws[widx] += 2.f * f;
          val[q] = hb + cs * f;
        }
      }
      half4v th, tl;
#pragma unroll
      for (int q = 0; q < 4; ++q) {
        _Float16 hh = (_Float16)val[q];
        th[q] = hh;
        tl[q] = (_Float16)(val[q] - (float)hh);
      }
      int ta = col >> 5;
      size_t hbase = (((size_t)b * 32 + mq) * 8 + ta) * 1024;
      int cb = ((col & 31) >> 3) * 32 + (ii0 & 31);
      int offc = col & 7;
#pragma unroll
      for (int q = 0; q < 4; ++q) {
        hHt[hbase + (size_t)(cb + q) * 8 + offc] = th[q];
        hLt[hbase + (size_t)(cb + q) * 8 + offc] = tl[q];
      }
      size_t tbase = ((size_t)b * 32 + mq) * 8192;
      int gk = (ii0 & 31) >> 3;
      *(half4v*)(hTw + tbase + (size_t)(gk * 256 + col) * 8 + (ii0 & 7)) = th;
    }
  }
#undef STAGE_B
#undef STAGE_AHL
#undef STAGE_AGG
}

// ---------------------------------------------------------------------------
extern "C" void kernel_launch(void* const* d_in, const int* in_sizes, int n_in,
                              void* d_out, int out_size, void* d_ws, size_t ws_size,
                              hipStream_t stream) {
  const float* h0 = (const float*)d_in[0];
  const float* tg = (const float*)d_in[1];
  const float* adj = (const float*)d_in[2];
  const float* W1 = (const float*)d_in[3];
  const float* b1 = (const float*)d_in[4];
  const float* W2 = (const float*)d_in[5];
  const float* b2 = (const float*)d_in[6];
  float* out = (float*)d_out;

  const size_t CD = (size_t)NC * ND;  // 262144
  char* w = (char*)d_ws;
  float* invdeg = (float*)w;     w += (size_t)16384 * 4;
  float* accws = (float*)w;      w += (size_t)NB * CD * 4;
  _Float16* adjT = (_Float16*)w; w += (size_t)NB * NC * NC * 2;
  _Float16* hHt = (_Float16*)w;  w += (size_t)NB * CD * 2;
  _Float16* hLt = (_Float16*)w;  w += (size_t)NB * CD * 2;
  _Float16* hTa = (_Float16*)w;  w += (size_t)NB * CD * 2;
  _Float16* hTb = (_Float16*)w;  w += (size_t)NB * CD * 2;
  _Float16* aggT = (_Float16*)w; w += (size_t)NB * CD * 2;
  _Float16* W1Tt = (_Float16*)w; w += (size_t)256 * 512 * 2;
  _Float16* W2Tt = (_Float16*)w; w += (size_t)256 * 256 * 2;

  k_copy_h0<<<dim3(4096), dim3(256), 0, stream>>>(h0, out);
  k_deg<<<dim3(4096), dim3(256), 0, stream>>>(adj, invdeg);
  k_split_adj<<<dim3(16384), dim3(256), 0, stream>>>(adj, adjT);
  k_split_w<<<dim3(192), dim3(256), 0, stream>>>(W1, W2, W1Tt, W2Tt);
  k_htsplit<<<dim3(4096), dim3(256), 0, stream>>>(h0, hHt, hLt, hTa);

  int par = 0;
  for (int s = 0; s < NT_ - 1; ++s) {
    for (int st = 0; st < 4; ++st) {
      _Float16* hTr = par ? hTb : hTa;
      _Float16* hTn = par ? hTa : hTb;
      k_agg<<<dim3(512), dim3(256), 0, stream>>>(adjT, hTr, invdeg, aggT);
      k_mlp<<<dim3(512), dim3(512), 0, stream>>>(hHt, hLt, aggT, hTn, W1Tt, W2Tt,
                                                 W1, b1, b2, tg, s, st, out, accws);
      par ^= 1;
    }
  }
}

// Round 14
// 1569.252 us; speedup vs baseline: 1.2060x; 1.2060x over previous
//
#include <hip/hip_runtime.h>
#include <math.h>

// Problem dims
#define NB   16
#define NC   1024
#define ND   256
#define NT_  9
#define TDIM 32

typedef _Float16 half8 __attribute__((ext_vector_type(8)));
typedef _Float16 half4v __attribute__((ext_vector_type(4)));
typedef float f32x4 __attribute__((ext_vector_type(4)));

#define GLL(gp, lp)                                                            \
  __builtin_amdgcn_global_load_lds(                                            \
      (const __attribute__((address_space(1))) void*)(gp),                     \
      (__attribute__((address_space(3))) void*)(lp), 16, 0, 0)

#define GLL4(gp, lp)                                                           \
  __builtin_amdgcn_global_load_lds(                                            \
      (const __attribute__((address_space(1))) void*)(gp),                     \
      (__attribute__((address_space(3))) void*)(lp), 4, 0, 0)

#define MFMA16(A, B, C) __builtin_amdgcn_mfma_f32_16x16x32_f16(A, B, C, 0, 0, 0)

// counted-vmcnt barrier: wait for all but the N newest vmem ops, then raw
// barrier. Prefetched loads stay in flight. sched_barrier pins ordering.
#define VBAR(N)                                                                \
  do {                                                                         \
    asm volatile("s_waitcnt vmcnt(" #N ")" ::: "memory");                      \
    __builtin_amdgcn_s_barrier();                                              \
    asm volatile("" ::: "memory");                                             \
    __builtin_amdgcn_sched_barrier(0);                                         \
  } while (0)

// post-compute barrier (no waitcnt): protects LDS buffers before re-staging
#define BAR2()                                                                 \
  do {                                                                         \
    asm volatile("" ::: "memory");                                             \
    __builtin_amdgcn_s_barrier();                                              \
    asm volatile("" ::: "memory");                                             \
  } while (0)

// LDS-visibility barrier (ds_write -> ds_read) WITHOUT draining vmcnt
#define LBAR()                                                                 \
  do {                                                                         \
    asm volatile("s_waitcnt lgkmcnt(0)" ::: "memory");                         \
    __builtin_amdgcn_s_barrier();                                              \
    asm volatile("" ::: "memory");                                             \
    __builtin_amdgcn_sched_barrier(0);                                         \
  } while (0)

// Tiled panel layouts (16B-chunk order == LDS image):
//  A-tile (32 rows x 32 k) = 1024 halves: element (row,k) ->
//    (((k&31)>>3)*32 + row)*8 + (k&7)
//  B-tile (256 n x 32 k) = 8192 halves: element (n,k) ->
//    (((k&31)>>3)*256 + n)*8 + (k&7)

// ---------------------------------------------------------------------------
__global__ __launch_bounds__(256) void k_copy_h0(const float* __restrict__ h0,
                                                 float* __restrict__ out) {
  size_t idx = (size_t)blockIdx.x * blockDim.x + threadIdx.x;
  size_t fe = idx * 4;
  size_t b = fe / ((size_t)NC * ND);
  size_t rem = fe % ((size_t)NC * ND);
  float4 v = *(const float4*)(h0 + fe);
  *(float4*)(out + (b * NT_) * (size_t)NC * ND + rem) = v;
}

// ---------------------------------------------------------------------------
__global__ __launch_bounds__(256) void k_deg(const float* __restrict__ adj,
                                             float* __restrict__ invdeg) {
  int wave = threadIdx.x >> 6;
  int lane = threadIdx.x & 63;
  int row = blockIdx.x * 4 + wave;
  const float* p = adj + (size_t)row * NC;
  float s = 0.f;
#pragma unroll
  for (int q = 0; q < 4; ++q) {
    float4 v = *(const float4*)(p + q * 256 + lane * 4);
    s += v.x + v.y + v.z + v.w;
  }
#pragma unroll
  for (int off = 32; off; off >>= 1) s += __shfl_down(s, off);
  if (lane == 0) invdeg[row] = 1.f / fmaxf(s, 1.f);
}

// ---------------------------------------------------------------------------
// adj f32 -> fp16, A-tiled: adjT[b][mq(32)][t(32)] each 1024 halves
__global__ __launch_bounds__(256) void k_split_adj(const float* __restrict__ adj,
                                                   _Float16* __restrict__ adjT) {
  int i = blockIdx.x * 256 + threadIdx.x;
  int k0 = (i & 255) * 4;
  int c = (i >> 8) & 1023;
  int b = i >> 18;
  float4 v = *(const float4*)(adj + (((size_t)b * NC + c) << 10) + k0);
  half4v h;
  h[0] = (_Float16)v.x; h[1] = (_Float16)v.y;
  h[2] = (_Float16)v.z; h[3] = (_Float16)v.w;
  int mq = c >> 5, t = k0 >> 5;
  size_t base = ((((size_t)b * 32 + mq) * 32) + t) * 1024;
  int chunk = ((k0 & 31) >> 3) * 32 + (c & 31);
  *(half4v*)(adjT + base + chunk * 8 + (k0 & 7)) = h;
}

// ---------------------------------------------------------------------------
// W1[0:512]^T, W2^T -> fp16, B-tiled: W1Tt[16 tiles][8192], W2Tt[8][8192]
__global__ __launch_bounds__(256) void k_split_w(const float* __restrict__ W1,
                                                 const float* __restrict__ W2,
                                                 _Float16* __restrict__ W1Tt,
                                                 _Float16* __restrict__ W2Tt) {
  int blk = blockIdx.x;
  int tid = threadIdx.x;
  if (blk < 128) {
    int i = blk * 256 + tid;
    int n = i & 255, k0 = (i >> 8) * 4;
    half4v h;
#pragma unroll
    for (int q = 0; q < 4; ++q) h[q] = (_Float16)W1[(size_t)(k0 + q) * ND + n];
    int t = k0 >> 5;
    int chunk = ((k0 & 31) >> 3) * 256 + n;
    *(half4v*)(W1Tt + (size_t)t * 8192 + chunk * 8 + (k0 & 7)) = h;
  } else {
    int i = (blk - 128) * 256 + tid;
    int n = i & 255, k0 = (i >> 8) * 4;
    half4v h;
#pragma unroll
    for (int q = 0; q < 4; ++q) h[q] = (_Float16)W2[(size_t)(k0 + q) * ND + n];
    int t = k0 >> 5;
    int chunk = ((k0 & 31) >> 3) * 256 + n;
    *(half4v*)(W2Tt + (size_t)t * 8192 + chunk * 8 + (k0 & 7)) = h;
  }
}

// ---------------------------------------------------------------------------
// one-time: h0 -> hHt/hLt (A-tiled [b][mq][ta(8)][1024]) + hTt (B-tiled
// [b][t(32)][8192], rows n=d, k=c)
__global__ __launch_bounds__(256) void k_htsplit(const float* __restrict__ src,
                                                 _Float16* __restrict__ hHt,
                                                 _Float16* __restrict__ hLt,
                                                 _Float16* __restrict__ hTt) {
  int i = blockIdx.x * 256 + threadIdx.x;
  int d0 = (i & 63) * 4;
  int c = (i >> 6) & 1023;
  int b = i >> 16;
  float4 v = *(const float4*)(src + (((size_t)b * NC + c) << 8) + d0);
  float vv[4] = {v.x, v.y, v.z, v.w};
  half4v hh, ll;
#pragma unroll
  for (int q = 0; q < 4; ++q) {
    _Float16 h = (_Float16)vv[q];
    hh[q] = h;
    ll[q] = (_Float16)(vv[q] - (float)h);
  }
  int mq = c >> 5, ta = d0 >> 5;
  size_t abase = ((((size_t)b * 32 + mq) * 8) + ta) * 1024;
  int achunk = ((d0 & 31) >> 3) * 32 + (c & 31);
  *(half4v*)(hHt + abase + achunk * 8 + (d0 & 7)) = hh;
  *(half4v*)(hLt + abase + achunk * 8 + (d0 & 7)) = ll;
  size_t tbase = ((size_t)b * 32 + mq) * 8192;
  int gk = (c & 31) >> 3, offc = c & 7;
#pragma unroll
  for (int q = 0; q < 4; ++q)
    hTt[tbase + (size_t)(gk * 256 + d0 + q) * 8 + offc] = hh[q];
}

// ---------------------------------------------------------------------------
// k_stage: one fused RK4 stage, counted-vmcnt 3-deep pipeline on pre-tiled
// panels. grid 512 (XCD-swizzled), 512 thr = 8 waves along N, tile 32x256.
// Global step S = 0..55: phase0 S=0..31 (agg = invdeg*adj@h, 1p), phaseA
// S=32..47 (u = tanh([h|agg]@W1hi+b1eff); h 2p, agg 1p), phaseB S=48..55
// (f = u@W2hi). Loads for S+2 issued at S; VBAR(count of S+1,S+2 loads);
// never drain vmcnt to 0 inside the loops.
// Per-thread uniform load counts n(S): S<32: 3; 32..39: 4; 40..55: 2.
__global__ __launch_bounds__(512, 4) void k_stage(
    const _Float16* __restrict__ adjT,
    _Float16* __restrict__ hHt, _Float16* __restrict__ hLt,
    const _Float16* __restrict__ hTr, _Float16* __restrict__ hTw,
    const float* __restrict__ invdeg,
    const _Float16* __restrict__ W1Tt, const _Float16* __restrict__ W2Tt,
    const float* __restrict__ W1, const float* __restrict__ b1,
    const float* __restrict__ b2, const float* __restrict__ tg,
    int step, int stage, float* __restrict__ out, float* __restrict__ accws) {
  __shared__ __align__(16) _Float16 Bs3[3][8192];  // 48 KB B, 3-deep
  __shared__ __align__(16) _Float16 As3[3][2048];  // 12 KB A (hi|lo), 3-deep
  __shared__ __align__(16) _Float16 POOL[8192];    // 16 KB aggS -> uS
  __shared__ float te_s[TDIM];
  __shared__ float b1s[256];
  _Float16* aggS = POOL;
  _Float16* uS = POOL;  // alias; disjoint lifetimes

  const int tid = threadIdx.x;
  const int lane = tid & 63, wid = tid >> 6;  // 8 waves along N
  const int g = lane >> 4, r = lane & 15, rg = (lane >> 4) * 4;
  // swizzle: batch b's 32 blocks share id mod 8 -> one XCD
  const int p = blockIdx.x;
  const int b = ((p >> 3) >> 5) * 8 + (p & 7);
  const int mq = (p >> 3) & 31;

  const _Float16* adjB = adjT + (((size_t)b * 32 + mq) * 32) * 1024;
  const _Float16* hTb = hTr + (size_t)b * 32 * 8192;
  const _Float16* hHb = hHt + (((size_t)b * 32 + mq) * 8) * 1024;
  const _Float16* hLb = hLt + (((size_t)b * 32 + mq) * 8) * 1024;

  f32x4 acc[2][2] = {};

  // hoist invdeg to registers BEFORE any GLL (keeps loops free of compiler
  // VMEM so the counted-vmcnt math stays exact)
  float iv[2][4];
#pragma unroll
  for (int i = 0; i < 2; ++i)
#pragma unroll
    for (int q = 0; q < 4; ++q)
      iv[i][q] = invdeg[b * NC + mq * 32 + i * 16 + rg + q];

// coalesced B-tile staging: 8192 halves contiguous; 2 GLL16/thread
#define STAGE_B(SRC, DST)                                                      \
  do {                                                                         \
    GLL((SRC) + (size_t)tid * 8, (DST) + (size_t)tid * 8);                     \
    GLL((SRC) + (size_t)(512 + tid) * 8, (DST) + (size_t)(512 + tid) * 8);     \
  } while (0)

  // issue loads for global step S2 into buffers S2%3 (uniform per thread)
  auto issue = [&](int S2) {
    if (S2 < 32) {
      GLL4(adjB + (size_t)S2 * 1024 + tid * 2, As3[S2 % 3] + (size_t)tid * 2);
      STAGE_B(hTb + (size_t)S2 * 8192, Bs3[S2 % 3]);
    } else if (S2 < 48) {
      int ta = S2 - 32;
      if (ta < 8) {
        GLL4(hHb + (size_t)ta * 1024 + tid * 2, As3[S2 % 3] + (size_t)tid * 2);
        GLL4(hLb + (size_t)ta * 1024 + tid * 2,
             As3[S2 % 3] + 1024 + (size_t)tid * 2);
      }
      STAGE_B(W1Tt + (size_t)ta * 8192, Bs3[S2 % 3]);
    } else if (S2 < 56) {
      STAGE_B(W2Tt + (size_t)(S2 - 48) * 8192, Bs3[S2 % 3]);
    }
  };

  // ---- prologue: issue S=0,1; time embedding; b1eff ----
  issue(0);
  issue(1);
  if (tid < 16) {
    float t0 = tg[step], t1 = tg[step + 1];
    float frac = (stage == 0) ? 0.f : ((stage == 3) ? 1.f : 0.5f);
    float t = t0 + frac * (t1 - t0);
    float f = expf(-logf(10000.f) * (float)tid / 16.f);
    te_s[tid] = sinf(t * f);
    te_s[tid + 16] = cosf(t * f);
  }
  LBAR();
  if (tid < 256) {
    float s = b1[tid];
#pragma unroll
    for (int q = 0; q < TDIM; ++q)
      s = fmaf(te_s[q], W1[(size_t)(512 + q) * ND + tid], s);
    b1s[tid] = s;
  }

  // ---- phase 0: S=0..31, 1-product ----
  for (int t = 0; t < 32; ++t) {
    int cur = t % 3;
    issue(t + 2);
    if (t < 30) VBAR(6);
    else if (t == 30) VBAR(7);
    else VBAR(8);
    half8 Af[2], Bf[2];
#pragma unroll
    for (int i = 0; i < 2; ++i)
      Af[i] = ((const half8*)As3[cur])[g * 32 + i * 16 + r];
#pragma unroll
    for (int j = 0; j < 2; ++j)
      Bf[j] = ((const half8*)Bs3[cur])[g * 256 + wid * 32 + j * 16 + r];
#pragma unroll
    for (int i = 0; i < 2; ++i)
#pragma unroll
      for (int j = 0; j < 2; ++j) acc[i][j] = MFMA16(Af[i], Bf[j], acc[i][j]);
    BAR2();
  }
  // phase0 epilogue: invdeg scale -> aggS (hi)
#pragma unroll
  for (int i = 0; i < 2; ++i) {
#pragma unroll
    for (int j = 0; j < 2; ++j) {
      int d = wid * 32 + j * 16 + r;
#pragma unroll
      for (int q = 0; q < 4; ++q) {
        int lr = i * 16 + rg + q;
        float v = acc[i][j][q] * iv[i][q];
        aggS[((d >> 3) * 32 + lr) * 8 + (d & 7)] = (_Float16)v;
      }
      acc[i][j] = (f32x4){0.f, 0.f, 0.f, 0.f};
    }
  }
  LBAR();  // aggS visible; phaseA prefetch stays in flight

  // ---- phase A: S=32..47 over [h | agg]; B = W1T-hi ----
  for (int ta = 0; ta < 16; ++ta) {
    int S = 32 + ta;
    int cur = S % 3;
    issue(S + 2);
    if (ta < 6) VBAR(8);
    else if (ta == 6) VBAR(6);
    else VBAR(4);
    half8 AH[2], AL[2], Bf[2];
    const bool hasL = (ta < 8);
    if (hasL) {
#pragma unroll
      for (int i = 0; i < 2; ++i) {
        AH[i] = ((const half8*)As3[cur])[g * 32 + i * 16 + r];
        AL[i] = ((const half8*)(As3[cur] + 1024))[g * 32 + i * 16 + r];
      }
    } else {
#pragma unroll
      for (int i = 0; i < 2; ++i)
        AH[i] = ((const half8*)aggS)[((ta - 8) * 4 + g) * 32 + i * 16 + r];
    }
#pragma unroll
    for (int j = 0; j < 2; ++j)
      Bf[j] = ((const half8*)Bs3[cur])[g * 256 + wid * 32 + j * 16 + r];
#pragma unroll
    for (int i = 0; i < 2; ++i)
#pragma unroll
      for (int j = 0; j < 2; ++j) {
        acc[i][j] = MFMA16(AH[i], Bf[j], acc[i][j]);
        if (hasL) acc[i][j] = MFMA16(AL[i], Bf[j], acc[i][j]);
      }
    BAR2();
  }
  // transition: uS = tanh(acc + b1eff) (aliases dead aggS)
#pragma unroll
  for (int i = 0; i < 2; ++i) {
#pragma unroll
    for (int j = 0; j < 2; ++j) {
      int col = wid * 32 + j * 16 + r;
#pragma unroll
      for (int q = 0; q < 4; ++q) {
        int row = i * 16 + rg + q;
        float v = tanhf(acc[i][j][q] + b1s[col]);
        uS[((col >> 3) * 32 + row) * 8 + (col & 7)] = (_Float16)v;
      }
      acc[i][j] = (f32x4){0.f, 0.f, 0.f, 0.f};
    }
  }
  LBAR();  // uS visible; phaseB prefetch stays in flight

  // ---- phase B: S=48..55 over u; B = W2T-hi ----
  for (int tb = 0; tb < 8; ++tb) {
    int S = 48 + tb;
    int cur = S % 3;
    issue(S + 2);
    if (tb < 6) VBAR(4);
    else if (tb == 6) VBAR(2);
    else VBAR(0);
    half8 Af[2], Bf[2];
#pragma unroll
    for (int i = 0; i < 2; ++i)
      Af[i] = ((const half8*)uS)[(tb * 4 + g) * 32 + i * 16 + r];
#pragma unroll
    for (int j = 0; j < 2; ++j)
      Bf[j] = ((const half8*)Bs3[cur])[g * 256 + wid * 32 + j * 16 + r];
#pragma unroll
    for (int i = 0; i < 2; ++i)
#pragma unroll
      for (int j = 0; j < 2; ++j) acc[i][j] = MFMA16(Af[i], Bf[j], acc[i][j]);
    BAR2();
  }
  // ---- RK4 epilogue ----
  const float t0 = tg[step], t1 = tg[step + 1];
  const float dt = t1 - t0;
  const float cs = (stage == 2) ? dt : 0.5f * dt;
#pragma unroll
  for (int i = 0; i < 2; ++i) {
#pragma unroll
    for (int j = 0; j < 2; ++j) {
      int col = wid * 32 + j * 16 + r;
      float bb2 = b2[col];
      int ii0 = mq * 32 + i * 16 + rg;
      size_t hrow = (((size_t)b * NT_ + step) * NC + ii0) * (size_t)ND + col;
      size_t wrow = ((size_t)b * NC + ii0) * (size_t)ND + col;
      float val[4];
#pragma unroll
      for (int q = 0; q < 4; ++q) {
        float f = acc[i][j][q] + bb2;
        float hb = out[hrow + (size_t)q * ND];
        size_t widx = wrow + (size_t)q * ND;
        if (stage == 0) {
          accws[widx] = f;
          val[q] = hb + cs * f;
        } else if (stage == 3) {
          float hn = hb + (dt / 6.f) * (accws[widx] + f);
          out[hrow + (size_t)NC * ND + (size_t)q * ND] = hn;
          val[q] = hn;
        } else {
          accws[widx] += 2.f * f;
          val[q] = hb + cs * f;
        }
      }
      half4v th, tl;
#pragma unroll
      for (int q = 0; q < 4; ++q) {
        _Float16 hh = (_Float16)val[q];
        th[q] = hh;
        tl[q] = (_Float16)(val[q] - (float)hh);
      }
      int ta = col >> 5;
      size_t hbase = (((size_t)b * 32 + mq) * 8 + ta) * 1024;
      int cb = ((col & 31) >> 3) * 32 + (ii0 & 31);
      int offc = col & 7;
#pragma unroll
      for (int q = 0; q < 4; ++q) {
        hHt[hbase + (size_t)(cb + q) * 8 + offc] = th[q];
        hLt[hbase + (size_t)(cb + q) * 8 + offc] = tl[q];
      }
      size_t tbase = ((size_t)b * 32 + mq) * 8192;
      int gk = (ii0 & 31) >> 3;
      *(half4v*)(hTw + tbase + (size_t)(gk * 256 + col) * 8 + (ii0 & 7)) = th;
    }
  }
#undef STAGE_B
}

// ---------------------------------------------------------------------------
extern "C" void kernel_launch(void* const* d_in, const int* in_sizes, int n_in,
                              void* d_out, int out_size, void* d_ws, size_t ws_size,
                              hipStream_t stream) {
  const float* h0 = (const float*)d_in[0];
  const float* tg = (const float*)d_in[1];
  const float* adj = (const float*)d_in[2];
  const float* W1 = (const float*)d_in[3];
  const float* b1 = (const float*)d_in[4];
  const float* W2 = (const float*)d_in[5];
  const float* b2 = (const float*)d_in[6];
  float* out = (float*)d_out;

  const size_t CD = (size_t)NC * ND;  // 262144
  char* w = (char*)d_ws;
  float* invdeg = (float*)w;     w += (size_t)16384 * 4;
  float* accws = (float*)w;      w += (size_t)NB * CD * 4;
  _Float16* adjT = (_Float16*)w; w += (size_t)NB * NC * NC * 2;
  _Float16* hHt = (_Float16*)w;  w += (size_t)NB * CD * 2;
  _Float16* hLt = (_Float16*)w;  w += (size_t)NB * CD * 2;
  _Float16* hTa = (_Float16*)w;  w += (size_t)NB * CD * 2;
  _Float16* hTb = (_Float16*)w;  w += (size_t)NB * CD * 2;
  _Float16* W1Tt = (_Float16*)w; w += (size_t)256 * 512 * 2;
  _Float16* W2Tt = (_Float16*)w; w += (size_t)256 * 256 * 2;

  k_copy_h0<<<dim3(4096), dim3(256), 0, stream>>>(h0, out);
  k_deg<<<dim3(4096), dim3(256), 0, stream>>>(adj, invdeg);
  k_split_adj<<<dim3(16384), dim3(256), 0, stream>>>(adj, adjT);
  k_split_w<<<dim3(192), dim3(256), 0, stream>>>(W1, W2, W1Tt, W2Tt);
  k_htsplit<<<dim3(4096), dim3(256), 0, stream>>>(h0, hHt, hLt, hTa);

  int par = 0;
  for (int s = 0; s < NT_ - 1; ++s) {
    for (int st = 0; st < 4; ++st) {
      k_stage<<<dim3(512), dim3(512), 0, stream>>>(
          adjT, hHt, hLt, par ? hTb : hTa, par ? hTa : hTb, invdeg, W1Tt, W2Tt,
          W1, b1, b2, tg, s, st, out, accws);
      par ^= 1;
    }
  }
}